// Round 11
// baseline (253.754 us; speedup 1.0000x reference)
//
#include <hip/hip_runtime.h>
#include <math.h>

typedef unsigned short u16;
typedef unsigned int u32;
typedef __attribute__((ext_vector_type(8))) __bf16 bf16x8;
typedef __attribute__((ext_vector_type(4))) float f32x4;

#define DEVI __device__ __forceinline__

DEVI u16 f2bf(float f){
  u32 b = __builtin_bit_cast(u32, f);
  return (u16)((b + 0x7FFFu + ((b >> 16) & 1u)) >> 16);
}

DEVI f32x4 mfma16(bf16x8 a, bf16x8 b, f32x4 c){
  return __builtin_amdgcn_mfma_f32_16x16x32_bf16(a, b, c, 0, 0, 0);
}

// async global->LDS, 16B per lane; LDS dest = wave-uniform base + lane*16.
DEVI void gload16(const u16* g, u16* l){
  __builtin_amdgcn_global_load_lds(
      (const __attribute__((address_space(1))) u32*)g,
      (__attribute__((address_space(3))) u32*)l,
      16, 0, 0);
}

DEVI void phase_bar(){
  __builtin_amdgcn_sched_barrier(0);
  __builtin_amdgcn_s_barrier();
  __builtin_amdgcn_sched_barrier(0);
}

// ---------------- f32 -> bf16 convert (4 elems/thread) ----------------
__global__ __launch_bounds__(256) void cvt_kernel(const float* __restrict__ in,
                                                  u16* __restrict__ out, int n4){
  int i = blockIdx.x * 256 + threadIdx.x;
  if (i >= n4) return;
  float4 v = reinterpret_cast<const float4*>(in)[i];
  u32 lo = (u32)f2bf(v.x) | ((u32)f2bf(v.y) << 16);
  u32 hi = (u32)f2bf(v.z) | ((u32)f2bf(v.w) << 16);
  reinterpret_cast<uint2*>(out)[i] = make_uint2(lo, hi);
}

// ---------------- LayerNorm: f32 in, bf16 out, row length 1024 ----------------
__global__ __launch_bounds__(256) void ln_kernel(const float* __restrict__ x,
                                                 const float* __restrict__ w,
                                                 const float* __restrict__ b,
                                                 u16* __restrict__ out){
  int row = blockIdx.x;
  int tid = threadIdx.x;
  const float4 v = reinterpret_cast<const float4*>(x + (size_t)row * 1024)[tid];
  float s  = v.x + v.y + v.z + v.w;
  float ss = v.x*v.x + v.y*v.y + v.z*v.z + v.w*v.w;
  #pragma unroll
  for (int m = 1; m < 64; m <<= 1){
    s  += __shfl_xor(s,  m, 64);
    ss += __shfl_xor(ss, m, 64);
  }
  __shared__ float red[8];
  int wid = tid >> 6, lane = tid & 63;
  if (lane == 0){ red[wid] = s; red[4 + wid] = ss; }
  __syncthreads();
  s  = red[0] + red[1] + red[2] + red[3];
  ss = red[4] + red[5] + red[6] + red[7];
  float mu   = s * (1.0f/1024.0f);
  float var  = ss * (1.0f/1024.0f) - mu*mu;
  float rstd = rsqrtf(var + 1e-5f);
  const float4 wv = reinterpret_cast<const float4*>(w)[tid];
  const float4 bv = reinterpret_cast<const float4*>(b)[tid];
  u32 lo = (u32)f2bf((v.x-mu)*rstd*wv.x + bv.x) | ((u32)f2bf((v.y-mu)*rstd*wv.y + bv.y) << 16);
  u32 hi = (u32)f2bf((v.z-mu)*rstd*wv.z + bv.z) | ((u32)f2bf((v.w-mu)*rstd*wv.w + bv.w) << 16);
  reinterpret_cast<uint2*>(out + (size_t)row*1024)[tid] = make_uint2(lo, hi);
}

// ---------------- reduce: out = x + bias + sum of 4 bf16 partials (f32 out) --------
__global__ __launch_bounds__(256) void reduce4_kernel(const u16* __restrict__ P,
                                                      const float* __restrict__ x,
                                                      const float* __restrict__ bias,
                                                      float* __restrict__ out){
  const size_t i8 = ((size_t)blockIdx.x * 256 + threadIdx.x) * 8;
  const size_t PS = (size_t)4096 * 1024;
  const int col0 = (int)(i8 & 1023);
  float acc[8];
  #pragma unroll
  for (int j = 0; j < 8; ++j) acc[j] = bias[col0 + j];
  #pragma unroll
  for (int s = 0; s < 4; ++s){
    uint4 d = *reinterpret_cast<const uint4*>(P + s*PS + i8);
    u32 w[4] = {d.x, d.y, d.z, d.w};
    #pragma unroll
    for (int j = 0; j < 8; ++j){
      u32 bits = ((w[j>>1] >> (16*(j&1))) & 0xFFFFu) << 16;
      acc[j] += __builtin_bit_cast(float, bits);
    }
  }
  float4 xv0 = reinterpret_cast<const float4*>(x + i8)[0];
  float4 xv1 = reinterpret_cast<const float4*>(x + i8)[1];
  acc[0]+=xv0.x; acc[1]+=xv0.y; acc[2]+=xv0.z; acc[3]+=xv0.w;
  acc[4]+=xv1.x; acc[5]+=xv1.y; acc[6]+=xv1.z; acc[7]+=xv1.w;
  reinterpret_cast<float4*>(out + i8)[0] = make_float4(acc[0],acc[1],acc[2],acc[3]);
  reinterpret_cast<float4*>(out + i8)[1] = make_float4(acc[4],acc[5],acc[6],acc[7]);
}

// ============ 256x256 8-phase GEMM: C = A(M x lda) * W(N x lda)^T, bf16 out ========
// (R9-verified schedule; lda/kLen/SPLIT generalization R10-verified)
template<bool HAS_BIAS, bool RELU, bool SPLIT>
__global__ __launch_bounds__(512, 2) void gemm256(const u16* __restrict__ A,
                                                  const u16* __restrict__ W,
                                                  const float* __restrict__ bias,
                                                  u16* __restrict__ outp,
                                                  int M, int N, int lda, int kLen){
  const int tid = threadIdx.x;
  const int wid = tid >> 6, lane = tid & 63;
  const int l16 = lane & 15, lhi = lane >> 4;
  const int wr = wid >> 2, wc = wid & 3;

  const int gx = gridDim.x, gy = gridDim.y;
  const int nwg = gx * gy * gridDim.z;
  const int bid = (blockIdx.z * gy + blockIdx.y) * gx + blockIdx.x;
  const int swz = (bid & 7) * (nwg >> 3) + (bid >> 3);
  const int col = swz % gx;
  const int rs  = swz / gx;
  const int row = rs % gy;
  const int ksp = rs / gy;
  const int brow = row * 256;
  const int bcol = col * 256;
  const size_t koff = (size_t)ksp * kLen;
  if (SPLIT) outp += (size_t)ksp * M * N;

  __shared__ u16 LDS[2][2][2][256*32];   // 128 KiB

  const int srow = tid >> 2;
  const int cg   = (tid & 3) ^ ((tid >> 3) & 3);
  const u16* gA = A + (size_t)(brow + srow) * lda + koff + cg*8;
  const u16* gW = W + (size_t)(bcol + srow) * lda + koff + cg*8;
  const size_t rK = (size_t)128 * lda;

#define STAGE(buf, mat, ks, t) do {                                   \
    const u16* _s = ((mat) ? gW : gA) + (t)*64 + (ks)*32;             \
    u16* _d = &LDS[buf][mat][ks][(wid*16)*32];                        \
    gload16(_s,      _d);                                             \
    gload16(_s + rK, _d + 128*32);                                    \
  } while(0)

  const int cswz = (lhi ^ ((l16 >> 1) & 3)) * 8;
  const int aoff = (wr*128 + l16)*32 + cswz;
  const int boff = (wc*64  + l16)*32 + cswz;
#define RDA(buf, ks, m) (*reinterpret_cast<const bf16x8*>(&LDS[buf][0][ks][aoff + (m)*512]))
#define RDB(buf, ks, n) (*reinterpret_cast<const bf16x8*>(&LDS[buf][1][ks][boff + (n)*512]))

  f32x4 acc[8][4] = {};
  bf16x8 a[8], b0, b1;

#define MFMA_PH(n0, n1) do {                                          \
    __builtin_amdgcn_s_setprio(1);                                    \
    _Pragma("unroll")                                                 \
    for (int m = 0; m < 8; ++m){                                      \
      acc[m][n0] = mfma16(a[m], b0, acc[m][n0]);                      \
      acc[m][n1] = mfma16(a[m], b1, acc[m][n1]);                      \
    }                                                                 \
    __builtin_amdgcn_s_setprio(0);                                    \
  } while(0)

  const int NITER = kLen >> 7;

  STAGE(0,0,0,0); STAGE(0,1,0,0); STAGE(0,0,1,0); STAGE(0,1,1,0);
  STAGE(1,0,0,1); STAGE(1,1,0,1);
  asm volatile("s_waitcnt vmcnt(4)" ::: "memory");
  phase_bar();

  for (int j = 0; j < NITER; ++j){
    const int t0 = 2*j, t1 = 2*j + 1;
    const bool more = (j + 1 < NITER);

    #pragma unroll
    for (int m = 0; m < 8; ++m) a[m] = RDA(0,0,m);
    b0 = RDB(0,0,0); b1 = RDB(0,0,1);
    STAGE(1,0,1,t1);
    phase_bar();
    MFMA_PH(0,1);
    phase_bar();
    b0 = RDB(0,0,2); b1 = RDB(0,0,3);
    STAGE(1,1,1,t1);
    phase_bar();
    MFMA_PH(2,3);
    phase_bar();
    #pragma unroll
    for (int m = 0; m < 8; ++m) a[m] = RDA(0,1,m);
    b0 = RDB(0,1,0); b1 = RDB(0,1,1);
    if (more) STAGE(0,0,0,t0+2);
    phase_bar();
    MFMA_PH(0,1);
    phase_bar();
    b0 = RDB(0,1,2); b1 = RDB(0,1,3);
    if (more){ STAGE(0,1,0,t0+2); asm volatile("s_waitcnt vmcnt(4)" ::: "memory"); }
    else     {                    asm volatile("s_waitcnt vmcnt(0)" ::: "memory"); }
    phase_bar();
    MFMA_PH(2,3);
    phase_bar();
    #pragma unroll
    for (int m = 0; m < 8; ++m) a[m] = RDA(1,0,m);
    b0 = RDB(1,0,0); b1 = RDB(1,0,1);
    if (more) STAGE(0,0,1,t0+2);
    phase_bar();
    MFMA_PH(0,1);
    phase_bar();
    b0 = RDB(1,0,2); b1 = RDB(1,0,3);
    if (more) STAGE(0,1,1,t0+2);
    phase_bar();
    MFMA_PH(2,3);
    phase_bar();
    #pragma unroll
    for (int m = 0; m < 8; ++m) a[m] = RDA(1,1,m);
    b0 = RDB(1,1,0); b1 = RDB(1,1,1);
    if (more) STAGE(1,0,0,t1+2);
    phase_bar();
    MFMA_PH(0,1);
    phase_bar();
    b0 = RDB(1,1,2); b1 = RDB(1,1,3);
    if (more){ STAGE(1,1,0,t1+2); asm volatile("s_waitcnt vmcnt(4)" ::: "memory"); }
    phase_bar();
    MFMA_PH(2,3);
    phase_bar();
  }
  __builtin_amdgcn_sched_barrier(0);

  const int row0 = brow + wr*128;
  const int col0 = bcol + wc*64;
  #pragma unroll
  for (int m = 0; m < 8; ++m){
    #pragma unroll
    for (int n = 0; n < 4; ++n){
      #pragma unroll
      for (int r = 0; r < 4; ++r){
        int row_ = row0 + m*16 + 4*lhi + r;
        int col_ = col0 + n*16 + l16;
        float v = acc[m][n][r];
        if constexpr (HAS_BIAS) v += bias[col_];
        if constexpr (RELU)     v = fmaxf(v, 0.0f);
        outp[(size_t)row_ * N + col_] = f2bf(v);
      }
    }
  }
#undef STAGE
#undef RDA
#undef RDB
#undef MFMA_PH
}

// ---------------- GEMM 128x128 (R7 structure) for proj ----------------
template<bool HAS_BIAS, bool HAS_RES, bool RELU, bool OUT_BF16>
__global__ __launch_bounds__(256) void gemm_bt(const u16* __restrict__ A,
                                               const u16* __restrict__ W,
                                               const float* __restrict__ bias,
                                               const float* __restrict__ res,
                                               void* __restrict__ outp,
                                               int M, int N, int K){
  const int tid = threadIdx.x;
  const int wid = tid >> 6, lane = tid & 63;
  const int l16 = lane & 15, lhi = lane >> 4;
  const int wr = wid >> 1, wc = wid & 1;

  const int gx = gridDim.x;
  const int nwg = gx * gridDim.y;
  const int bid = blockIdx.y * gx + blockIdx.x;
  const int swz = (bid & 7) * (nwg >> 3) + (bid >> 3);
  const int brow = (swz / gx) * 128;
  const int bcol = (swz % gx) * 128;

  __shared__ u16 As[2][128*32];
  __shared__ u16 Bs[2][128*32];

  const int srow = wid*32 + (lane >> 2);
  const int schk = lane & 3;
  const u16* gA0 = A + (size_t)(brow + srow)      * K + schk*8;
  const u16* gA1 = A + (size_t)(brow + srow + 16) * K + schk*8;
  const u16* gW0 = W + (size_t)(bcol + srow)      * K + schk*8;
  const u16* gW1 = W + (size_t)(bcol + srow + 16) * K + schk*8;
  const int ldsA0 = (wid*32)*32, ldsA1 = (wid*32 + 16)*32;

  f32x4 acc[4][4] = {};

  gload16(gA0, &As[0][ldsA0]);
  gload16(gA1, &As[0][ldsA1]);
  gload16(gW0, &Bs[0][ldsA0]);
  gload16(gW1, &Bs[0][ldsA1]);

  int cur = 0;
  for (int k0 = 0; k0 < K; k0 += 32){
    __syncthreads();
    if (k0 + 32 < K){
      gload16(gA0 + k0 + 32, &As[cur^1][ldsA0]);
      gload16(gA1 + k0 + 32, &As[cur^1][ldsA1]);
      gload16(gW0 + k0 + 32, &Bs[cur^1][ldsA0]);
      gload16(gW1 + k0 + 32, &Bs[cur^1][ldsA1]);
    }
    bf16x8 af[4], bfr[4];
    #pragma unroll
    for (int m = 0; m < 4; ++m)
      af[m]  = *reinterpret_cast<const bf16x8*>(&As[cur][(wr*64 + m*16 + l16)*32 + 8*lhi]);
    #pragma unroll
    for (int n = 0; n < 4; ++n)
      bfr[n] = *reinterpret_cast<const bf16x8*>(&Bs[cur][(wc*64 + n*16 + l16)*32 + 8*lhi]);
    #pragma unroll
    for (int m = 0; m < 4; ++m){
      #pragma unroll
      for (int n = 0; n < 4; ++n){
        acc[m][n] = mfma16(af[m], bfr[n], acc[m][n]);
      }
    }
    cur ^= 1;
  }

  const int row0 = brow + wr*64;
  const int col0 = bcol + wc*64;
  #pragma unroll
  for (int m = 0; m < 4; ++m){
    #pragma unroll
    for (int n = 0; n < 4; ++n){
      #pragma unroll
      for (int r = 0; r < 4; ++r){
        int row = row0 + m*16 + 4*lhi + r;
        int col = col0 + n*16 + l16;
        float v = acc[m][n][r];
        if constexpr (HAS_BIAS) v += bias[col];
        if constexpr (RELU)     v = fmaxf(v, 0.0f);
        if constexpr (HAS_RES)  v += res[(size_t)row * N + col];
        if constexpr (OUT_BF16) ((u16*)outp)[(size_t)row * N + col] = f2bf(v);
        else                    ((float*)outp)[(size_t)row * N + col] = v;
      }
    }
  }
}

// ---------------- causal flash attention (R6 dataflow; 1 qt/block, XCD-local) -------
// grid (32 bh, 32): blockIdx.x = bh  => linear id % 8 == bh % 8 => all 32 blocks of
// one (b,h) land on one XCD (4 bh/XCD x 512 KB KV = 2 MB, fits 4 MB L2).
// qt = 31 - blockIdx.y: heavy blocks dispatch first (LPT), short blocks backfill.
__global__ __launch_bounds__(256) void attn_kernel(const u16* __restrict__ qkv,
                                                   u16* __restrict__ att){
  const int bh = blockIdx.x;
  const int qt = 31 - blockIdx.y;
  const int bb = bh >> 4, hh = bh & 15;
  const int tid = threadIdx.x;
  const int wid = tid >> 6, lane = tid & 63;
  const int l16 = lane & 15, lhi = lane >> 4;
  const u16* base = qkv + (size_t)bb * 2048 * 3072 + (size_t)hh * 192;

  __shared__ u16 Ks[64*72];
  __shared__ u16 Vt[64*72];
  __shared__ u16 Ps[4*16*72];

  const int sr = tid >> 2;
  const int sc = tid & 3;
  const u16* stage_base = base + (size_t)sr * 3072 + sc*8;   // K at +0, V at +128

  const int qrow0 = qt * 64 + wid * 16;

  bf16x8 qf[2];
  {
    const u16* qp = base + (size_t)(qrow0 + l16) * 3072 + 64 + 8*lhi;
    qf[0] = *reinterpret_cast<const bf16x8*>(qp);
    qf[1] = *reinterpret_cast<const bf16x8*>(qp + 32);
  }

  f32x4 o[4] = {};
  float m_r[4], l_r[4];
  #pragma unroll
  for (int r = 0; r < 4; ++r){ m_r[r] = -INFINITY; l_r[r] = 0.0f; }

  const int nkt = qt + 1;

  uint4 kd0, kd1, vd0, vd1;
  {
    const u16* srow = stage_base;
    kd0 = *reinterpret_cast<const uint4*>(srow);
    kd1 = *reinterpret_cast<const uint4*>(srow + 32);
    vd0 = *reinterpret_cast<const uint4*>(srow + 128);
    vd1 = *reinterpret_cast<const uint4*>(srow + 160);
  }

  for (int kt = 0; kt < nkt; ++kt){
    __syncthreads();             // all waves done reading previous tile
    *reinterpret_cast<uint4*>(&Ks[sr*72 + sc*8])      = kd0;
    *reinterpret_cast<uint4*>(&Ks[sr*72 + sc*8 + 32]) = kd1;
    {
      u32 w0[4] = {vd0.x, vd0.y, vd0.z, vd0.w};
      u32 w1[4] = {vd1.x, vd1.y, vd1.z, vd1.w};
      const int ch0 = ((sr>>3) ^ sc)       << 3;
      const int ch1 = ((sr>>3) ^ (sc + 4)) << 3;
      #pragma unroll
      for (int j = 0; j < 8; ++j){
        int d0 = sc*8 + j;
        Vt[d0*72        + ch0 + (sr&7)] = (u16)(w0[j>>1] >> (16*(j&1)));
        Vt[(d0+32)*72   + ch1 + (sr&7)] = (u16)(w1[j>>1] >> (16*(j&1)));
      }
    }
    __syncthreads();             // tile staged

    if (kt + 1 < nkt){           // prefetch next tile during compute
      const u16* srow = stage_base + (size_t)(kt + 1) * 64 * 3072;
      kd0 = *reinterpret_cast<const uint4*>(srow);
      kd1 = *reinterpret_cast<const uint4*>(srow + 32);
      vd0 = *reinterpret_cast<const uint4*>(srow + 128);
      vd1 = *reinterpret_cast<const uint4*>(srow + 160);
    }

    const int kb = kt * 64;

    // ---- S = (Q K^T) * 0.125 ----
    f32x4 s_acc[4] = {};
    #pragma unroll
    for (int f = 0; f < 4; ++f){
      const u16* kp = &Ks[(f*16 + l16)*72 + 8*lhi];
      bf16x8 k0 = *reinterpret_cast<const bf16x8*>(kp);
      bf16x8 k1 = *reinterpret_cast<const bf16x8*>(kp + 32);
      s_acc[f] = mfma16(qf[0], k0, s_acc[f]);
      s_acc[f] = mfma16(qf[1], k1, s_acc[f]);
    }

    float sc_[4][4];
    #pragma unroll
    for (int f = 0; f < 4; ++f){
      #pragma unroll
      for (int r = 0; r < 4; ++r) sc_[f][r] = s_acc[f][r] * 0.125f;
    }

    if (kt == nkt - 1){          // diagonal tile: causal mask
      #pragma unroll
      for (int f = 0; f < 4; ++f){
        int col = kb + f*16 + l16;
        #pragma unroll
        for (int r = 0; r < 4; ++r){
          int row = qrow0 + 4*lhi + r;
          if (col > row) sc_[f][r] = -INFINITY;
        }
      }
    }

    // ---- online softmax (rows live in 16-lane groups) ----
    float alpha[4], p[4][4];
    #pragma unroll
    for (int r = 0; r < 4; ++r){
      float mx = fmaxf(fmaxf(sc_[0][r], sc_[1][r]), fmaxf(sc_[2][r], sc_[3][r]));
      #pragma unroll
      for (int m = 1; m < 16; m <<= 1) mx = fmaxf(mx, __shfl_xor(mx, m, 64));
      float mnew = fmaxf(m_r[r], mx);
      alpha[r] = __expf(m_r[r] - mnew);
      m_r[r] = mnew;
      float sum = 0.0f;
      #pragma unroll
      for (int f = 0; f < 4; ++f){ p[f][r] = __expf(sc_[f][r] - mnew); sum += p[f][r]; }
      #pragma unroll
      for (int m = 1; m < 16; m <<= 1) sum += __shfl_xor(sum, m, 64);
      l_r[r] = l_r[r] * alpha[r] + sum;
    }
    #pragma unroll
    for (int n = 0; n < 4; ++n){
      #pragma unroll
      for (int r = 0; r < 4; ++r) o[n][r] *= alpha[r];
    }

    // ---- P (D-layout) -> per-wave LDS as bf16, read back as A-fragments ----
    #pragma unroll
    for (int f = 0; f < 4; ++f){
      #pragma unroll
      for (int r = 0; r < 4; ++r)
        Ps[wid*1152 + (4*lhi + r)*72 + f*16 + l16] = f2bf(p[f][r]);
    }
    bf16x8 pa[2];
    pa[0] = *reinterpret_cast<const bf16x8*>(&Ps[wid*1152 + l16*72 + 8*lhi]);
    pa[1] = *reinterpret_cast<const bf16x8*>(&Ps[wid*1152 + l16*72 + 8*lhi + 32]);

    // ---- PV: B-fragments are contiguous b128 reads from swizzled-transposed V ----
    #pragma unroll
    for (int n = 0; n < 4; ++n){
      const int dv = n*16 + l16;
      const int dh = dv >> 3;
      #pragma unroll
      for (int s = 0; s < 2; ++s){
        const int ch = ((lhi + 4*s) ^ dh) << 3;
        bf16x8 vb = *reinterpret_cast<const bf16x8*>(&Vt[dv*72 + ch]);
        o[n] = mfma16(pa[s], vb, o[n]);
      }
    }
  }

  // ---- store O ----
  float inv_l[4];
  #pragma unroll
  for (int r = 0; r < 4; ++r) inv_l[r] = 1.0f / l_r[r];
  #pragma unroll
  for (int n = 0; n < 4; ++n){
    #pragma unroll
    for (int r = 0; r < 4; ++r){
      int row = qrow0 + 4*lhi + r;
      int col = hh*64 + n*16 + l16;
      att[(size_t)(bb*2048 + row) * 1024 + col] = f2bf(o[n][r] * inv_l[r]);
    }
  }
}

extern "C" void kernel_launch(void* const* d_in, const int* in_sizes, int n_in,
                              void* d_out, int out_size, void* d_ws, size_t ws_size,
                              hipStream_t stream){
  const float* x        = (const float*)d_in[0];
  const float* ln1_w    = (const float*)d_in[1];
  const float* ln1_b    = (const float*)d_in[2];
  const float* c_proj_w = (const float*)d_in[3];
  const float* proj_w   = (const float*)d_in[4];
  const float* proj_b   = (const float*)d_in[5];
  const float* ln2_w    = (const float*)d_in[6];
  const float* ln2_b    = (const float*)d_in[7];
  const float* ffn1_w   = (const float*)d_in[8];
  const float* ffn1_b   = (const float*)d_in[9];
  const float* ffn2_w   = (const float*)d_in[10];
  const float* ffn2_b   = (const float*)d_in[11];

  // Workspace layout (80 MiB). Late-dead buffers (Wqkv/Wproj/LNb/ACT2) are placed
  // contiguously at the tail so the ffn2 split-K bf16 partials (32 MiB) can reuse them.
  char* p = (char*)d_ws;
  u16* Wff1  = (u16*)p;  p += (size_t)4096*1024*2;   //  8 MiB (dead after ffn1)
  u16* Wff2  = (u16*)p;  p += (size_t)1024*4096*2;   //  8 MiB (dead after ffn2)
  u16* QKV   = (u16*)p;  p += (size_t)4096*3072*2;   // 24 MiB (FFN1 aliases after attn+proj)
  u16* ATT   = (u16*)p;  p += (size_t)4096*1024*2;   //  8 MiB
  u16* Wqkv  = (u16*)p;  p += (size_t)3072*1024*2;   //  6 MiB (dead after qkv gemm)
  u16* Wproj = (u16*)p;  p += (size_t)1024*1024*2;   //  2 MiB (dead after proj)
  u16* LNb   = (u16*)p;  p += (size_t)4096*1024*2;   //  8 MiB (dead after ffn1)
  float* ACT2= (float*)p;                            // 16 MiB (dead after ln2)
  u16* FFN1  = QKV;
  u16* PART  = Wqkv;     // 32 MiB: Wqkv+Wproj+LNb+ACT2, all dead by ffn2 time

  cvt_kernel<<<3072, 256, 0, stream>>>(c_proj_w, Wqkv, 786432);
  cvt_kernel<<<1024, 256, 0, stream>>>(proj_w,  Wproj, 262144);
  cvt_kernel<<<4096, 256, 0, stream>>>(ffn1_w,  Wff1, 1048576);
  cvt_kernel<<<4096, 256, 0, stream>>>(ffn2_w,  Wff2, 1048576);

  ln_kernel<<<4096, 256, 0, stream>>>(x, ln1_w, ln1_b, LNb);
  gemm256<false,false,false><<<dim3(12,16,1), 512, 0, stream>>>(LNb, Wqkv, nullptr, QKV, 4096, 3072, 1024, 1024);
  attn_kernel<<<dim3(32,32), 256, 0, stream>>>(QKV, ATT);
  gemm_bt<true ,true ,false,false><<<dim3(8,32), 256, 0, stream>>>(ATT, Wproj, proj_b, x, ACT2, 4096, 1024, 1024);
  ln_kernel<<<4096, 256, 0, stream>>>(ACT2, ln2_w, ln2_b, LNb);
  gemm256<true ,true ,false><<<dim3(16,16,1), 512, 0, stream>>>(LNb, Wff1, ffn1_b, FFN1, 4096, 4096, 1024, 1024);
  gemm256<false,false,true ><<<dim3(4,16,4), 512, 0, stream>>>(FFN1, Wff2, nullptr, PART, 4096, 1024, 4096, 1024);
  reduce4_kernel<<<2048, 256, 0, stream>>>(PART, x, ffn2_b, (float*)d_out);
}

// Round 12
// 249.242 us; speedup vs baseline: 1.0181x; 1.0181x over previous
//
#include <hip/hip_runtime.h>
#include <math.h>

typedef unsigned short u16;
typedef unsigned int u32;
typedef __attribute__((ext_vector_type(8))) __bf16 bf16x8;
typedef __attribute__((ext_vector_type(4))) float f32x4;

#define DEVI __device__ __forceinline__

DEVI u16 f2bf(float f){
  u32 b = __builtin_bit_cast(u32, f);
  return (u16)((b + 0x7FFFu + ((b >> 16) & 1u)) >> 16);
}

DEVI f32x4 mfma16(bf16x8 a, bf16x8 b, f32x4 c){
  return __builtin_amdgcn_mfma_f32_16x16x32_bf16(a, b, c, 0, 0, 0);
}

// async global->LDS, 16B per lane; LDS dest = wave-uniform base + lane*16.
DEVI void gload16(const u16* g, u16* l){
  __builtin_amdgcn_global_load_lds(
      (const __attribute__((address_space(1))) u32*)g,
      (__attribute__((address_space(3))) u32*)l,
      16, 0, 0);
}

DEVI void phase_bar(){
  __builtin_amdgcn_sched_barrier(0);
  __builtin_amdgcn_s_barrier();
  __builtin_amdgcn_sched_barrier(0);
}

// scale all 8 bf16 lanes of a fragment by a float constant (used once per block)
DEVI bf16x8 scale_bf16x8(bf16x8 v, float s){
  u32 w[4]; __builtin_memcpy(w, &v, 16);
  u32 o[4];
  #pragma unroll
  for (int i = 0; i < 4; ++i){
    float f0 = __builtin_bit_cast(float, (w[i] & 0xFFFFu) << 16) * s;
    float f1 = __builtin_bit_cast(float, w[i] & 0xFFFF0000u) * s;
    o[i] = (u32)f2bf(f0) | ((u32)f2bf(f1) << 16);
  }
  bf16x8 r; __builtin_memcpy(&r, o, 16);
  return r;
}

// ---------------- f32 -> bf16 convert (4 elems/thread) ----------------
__global__ __launch_bounds__(256) void cvt_kernel(const float* __restrict__ in,
                                                  u16* __restrict__ out, int n4){
  int i = blockIdx.x * 256 + threadIdx.x;
  if (i >= n4) return;
  float4 v = reinterpret_cast<const float4*>(in)[i];
  u32 lo = (u32)f2bf(v.x) | ((u32)f2bf(v.y) << 16);
  u32 hi = (u32)f2bf(v.z) | ((u32)f2bf(v.w) << 16);
  reinterpret_cast<uint2*>(out)[i] = make_uint2(lo, hi);
}

// ---------------- LayerNorm: f32 in, bf16 out, row length 1024 ----------------
__global__ __launch_bounds__(256) void ln_kernel(const float* __restrict__ x,
                                                 const float* __restrict__ w,
                                                 const float* __restrict__ b,
                                                 u16* __restrict__ out){
  int row = blockIdx.x;
  int tid = threadIdx.x;
  const float4 v = reinterpret_cast<const float4*>(x + (size_t)row * 1024)[tid];
  float s  = v.x + v.y + v.z + v.w;
  float ss = v.x*v.x + v.y*v.y + v.z*v.z + v.w*v.w;
  #pragma unroll
  for (int m = 1; m < 64; m <<= 1){
    s  += __shfl_xor(s,  m, 64);
    ss += __shfl_xor(ss, m, 64);
  }
  __shared__ float red[8];
  int wid = tid >> 6, lane = tid & 63;
  if (lane == 0){ red[wid] = s; red[4 + wid] = ss; }
  __syncthreads();
  s  = red[0] + red[1] + red[2] + red[3];
  ss = red[4] + red[5] + red[6] + red[7];
  float mu   = s * (1.0f/1024.0f);
  float var  = ss * (1.0f/1024.0f) - mu*mu;
  float rstd = rsqrtf(var + 1e-5f);
  const float4 wv = reinterpret_cast<const float4*>(w)[tid];
  const float4 bv = reinterpret_cast<const float4*>(b)[tid];
  u32 lo = (u32)f2bf((v.x-mu)*rstd*wv.x + bv.x) | ((u32)f2bf((v.y-mu)*rstd*wv.y + bv.y) << 16);
  u32 hi = (u32)f2bf((v.z-mu)*rstd*wv.z + bv.z) | ((u32)f2bf((v.w-mu)*rstd*wv.w + bv.w) << 16);
  reinterpret_cast<uint2*>(out + (size_t)row*1024)[tid] = make_uint2(lo, hi);
}

// ---------------- reduce: out = x + bias + sum of 4 bf16 partials (f32 out) --------
__global__ __launch_bounds__(256) void reduce4_kernel(const u16* __restrict__ P,
                                                      const float* __restrict__ x,
                                                      const float* __restrict__ bias,
                                                      float* __restrict__ out){
  const size_t i8 = ((size_t)blockIdx.x * 256 + threadIdx.x) * 8;
  const size_t PS = (size_t)4096 * 1024;
  const int col0 = (int)(i8 & 1023);
  float acc[8];
  #pragma unroll
  for (int j = 0; j < 8; ++j) acc[j] = bias[col0 + j];
  #pragma unroll
  for (int s = 0; s < 4; ++s){
    uint4 d = *reinterpret_cast<const uint4*>(P + s*PS + i8);
    u32 w[4] = {d.x, d.y, d.z, d.w};
    #pragma unroll
    for (int j = 0; j < 8; ++j){
      u32 bits = ((w[j>>1] >> (16*(j&1))) & 0xFFFFu) << 16;
      acc[j] += __builtin_bit_cast(float, bits);
    }
  }
  float4 xv0 = reinterpret_cast<const float4*>(x + i8)[0];
  float4 xv1 = reinterpret_cast<const float4*>(x + i8)[1];
  acc[0]+=xv0.x; acc[1]+=xv0.y; acc[2]+=xv0.z; acc[3]+=xv0.w;
  acc[4]+=xv1.x; acc[5]+=xv1.y; acc[6]+=xv1.z; acc[7]+=xv1.w;
  reinterpret_cast<float4*>(out + i8)[0] = make_float4(acc[0],acc[1],acc[2],acc[3]);
  reinterpret_cast<float4*>(out + i8)[1] = make_float4(acc[4],acc[5],acc[6],acc[7]);
}

// ============ 256x256 8-phase GEMM: C = A(M x lda) * W(N x lda)^T, bf16 out ========
// (R9-verified schedule; lda/kLen/SPLIT generalization R10-verified)
template<bool HAS_BIAS, bool RELU, bool SPLIT>
__global__ __launch_bounds__(512, 2) void gemm256(const u16* __restrict__ A,
                                                  const u16* __restrict__ W,
                                                  const float* __restrict__ bias,
                                                  u16* __restrict__ outp,
                                                  int M, int N, int lda, int kLen){
  const int tid = threadIdx.x;
  const int wid = tid >> 6, lane = tid & 63;
  const int l16 = lane & 15, lhi = lane >> 4;
  const int wr = wid >> 2, wc = wid & 3;

  const int gx = gridDim.x, gy = gridDim.y;
  const int nwg = gx * gy * gridDim.z;
  const int bid = (blockIdx.z * gy + blockIdx.y) * gx + blockIdx.x;
  const int swz = (bid & 7) * (nwg >> 3) + (bid >> 3);
  const int col = swz % gx;
  const int rs  = swz / gx;
  const int row = rs % gy;
  const int ksp = rs / gy;
  const int brow = row * 256;
  const int bcol = col * 256;
  const size_t koff = (size_t)ksp * kLen;
  if (SPLIT) outp += (size_t)ksp * M * N;

  __shared__ u16 LDS[2][2][2][256*32];   // 128 KiB

  const int srow = tid >> 2;
  const int cg   = (tid & 3) ^ ((tid >> 3) & 3);
  const u16* gA = A + (size_t)(brow + srow) * lda + koff + cg*8;
  const u16* gW = W + (size_t)(bcol + srow) * lda + koff + cg*8;
  const size_t rK = (size_t)128 * lda;

#define STAGE(buf, mat, ks, t) do {                                   \
    const u16* _s = ((mat) ? gW : gA) + (t)*64 + (ks)*32;             \
    u16* _d = &LDS[buf][mat][ks][(wid*16)*32];                        \
    gload16(_s,      _d);                                             \
    gload16(_s + rK, _d + 128*32);                                    \
  } while(0)

  const int cswz = (lhi ^ ((l16 >> 1) & 3)) * 8;
  const int aoff = (wr*128 + l16)*32 + cswz;
  const int boff = (wc*64  + l16)*32 + cswz;
#define RDA(buf, ks, m) (*reinterpret_cast<const bf16x8*>(&LDS[buf][0][ks][aoff + (m)*512]))
#define RDB(buf, ks, n) (*reinterpret_cast<const bf16x8*>(&LDS[buf][1][ks][boff + (n)*512]))

  f32x4 acc[8][4] = {};
  bf16x8 a[8], b0, b1;

#define MFMA_PH(n0, n1) do {                                          \
    __builtin_amdgcn_s_setprio(1);                                    \
    _Pragma("unroll")                                                 \
    for (int m = 0; m < 8; ++m){                                      \
      acc[m][n0] = mfma16(a[m], b0, acc[m][n0]);                      \
      acc[m][n1] = mfma16(a[m], b1, acc[m][n1]);                      \
    }                                                                 \
    __builtin_amdgcn_s_setprio(0);                                    \
  } while(0)

  const int NITER = kLen >> 7;

  STAGE(0,0,0,0); STAGE(0,1,0,0); STAGE(0,0,1,0); STAGE(0,1,1,0);
  STAGE(1,0,0,1); STAGE(1,1,0,1);
  asm volatile("s_waitcnt vmcnt(4)" ::: "memory");
  phase_bar();

  for (int j = 0; j < NITER; ++j){
    const int t0 = 2*j, t1 = 2*j + 1;
    const bool more = (j + 1 < NITER);

    #pragma unroll
    for (int m = 0; m < 8; ++m) a[m] = RDA(0,0,m);
    b0 = RDB(0,0,0); b1 = RDB(0,0,1);
    STAGE(1,0,1,t1);
    phase_bar();
    MFMA_PH(0,1);
    phase_bar();
    b0 = RDB(0,0,2); b1 = RDB(0,0,3);
    STAGE(1,1,1,t1);
    phase_bar();
    MFMA_PH(2,3);
    phase_bar();
    #pragma unroll
    for (int m = 0; m < 8; ++m) a[m] = RDA(0,1,m);
    b0 = RDB(0,1,0); b1 = RDB(0,1,1);
    if (more) STAGE(0,0,0,t0+2);
    phase_bar();
    MFMA_PH(0,1);
    phase_bar();
    b0 = RDB(0,1,2); b1 = RDB(0,1,3);
    if (more){ STAGE(0,1,0,t0+2); asm volatile("s_waitcnt vmcnt(4)" ::: "memory"); }
    else     {                    asm volatile("s_waitcnt vmcnt(0)" ::: "memory"); }
    phase_bar();
    MFMA_PH(2,3);
    phase_bar();
    #pragma unroll
    for (int m = 0; m < 8; ++m) a[m] = RDA(1,0,m);
    b0 = RDB(1,0,0); b1 = RDB(1,0,1);
    if (more) STAGE(0,0,1,t0+2);
    phase_bar();
    MFMA_PH(0,1);
    phase_bar();
    b0 = RDB(1,0,2); b1 = RDB(1,0,3);
    if (more) STAGE(0,1,1,t0+2);
    phase_bar();
    MFMA_PH(2,3);
    phase_bar();
    #pragma unroll
    for (int m = 0; m < 8; ++m) a[m] = RDA(1,1,m);
    b0 = RDB(1,1,0); b1 = RDB(1,1,1);
    if (more) STAGE(1,0,0,t1+2);
    phase_bar();
    MFMA_PH(0,1);
    phase_bar();
    b0 = RDB(1,1,2); b1 = RDB(1,1,3);
    if (more){ STAGE(1,1,0,t1+2); asm volatile("s_waitcnt vmcnt(4)" ::: "memory"); }
    phase_bar();
    MFMA_PH(2,3);
    phase_bar();
  }
  __builtin_amdgcn_sched_barrier(0);

  const int row0 = brow + wr*128;
  const int col0 = bcol + wc*64;
  #pragma unroll
  for (int m = 0; m < 8; ++m){
    #pragma unroll
    for (int n = 0; n < 4; ++n){
      #pragma unroll
      for (int r = 0; r < 4; ++r){
        int row_ = row0 + m*16 + 4*lhi + r;
        int col_ = col0 + n*16 + l16;
        float v = acc[m][n][r];
        if constexpr (HAS_BIAS) v += bias[col_];
        if constexpr (RELU)     v = fmaxf(v, 0.0f);
        outp[(size_t)row_ * N + col_] = f2bf(v);
      }
    }
  }
#undef STAGE
#undef RDA
#undef RDB
#undef MFMA_PH
}

// ---------------- GEMM 128x128 (R7 structure) for proj ----------------
template<bool HAS_BIAS, bool HAS_RES, bool RELU, bool OUT_BF16>
__global__ __launch_bounds__(256) void gemm_bt(const u16* __restrict__ A,
                                               const u16* __restrict__ W,
                                               const float* __restrict__ bias,
                                               const float* __restrict__ res,
                                               void* __restrict__ outp,
                                               int M, int N, int K){
  const int tid = threadIdx.x;
  const int wid = tid >> 6, lane = tid & 63;
  const int l16 = lane & 15, lhi = lane >> 4;
  const int wr = wid >> 1, wc = wid & 1;

  const int gx = gridDim.x;
  const int nwg = gx * gridDim.y;
  const int bid = blockIdx.y * gx + blockIdx.x;
  const int swz = (bid & 7) * (nwg >> 3) + (bid >> 3);
  const int brow = (swz / gx) * 128;
  const int bcol = (swz % gx) * 128;

  __shared__ u16 As[2][128*32];
  __shared__ u16 Bs[2][128*32];

  const int srow = wid*32 + (lane >> 2);
  const int schk = lane & 3;
  const u16* gA0 = A + (size_t)(brow + srow)      * K + schk*8;
  const u16* gA1 = A + (size_t)(brow + srow + 16) * K + schk*8;
  const u16* gW0 = W + (size_t)(bcol + srow)      * K + schk*8;
  const u16* gW1 = W + (size_t)(bcol + srow + 16) * K + schk*8;
  const int ldsA0 = (wid*32)*32, ldsA1 = (wid*32 + 16)*32;

  f32x4 acc[4][4] = {};

  gload16(gA0, &As[0][ldsA0]);
  gload16(gA1, &As[0][ldsA1]);
  gload16(gW0, &Bs[0][ldsA0]);
  gload16(gW1, &Bs[0][ldsA1]);

  int cur = 0;
  for (int k0 = 0; k0 < K; k0 += 32){
    __syncthreads();
    if (k0 + 32 < K){
      gload16(gA0 + k0 + 32, &As[cur^1][ldsA0]);
      gload16(gA1 + k0 + 32, &As[cur^1][ldsA1]);
      gload16(gW0 + k0 + 32, &Bs[cur^1][ldsA0]);
      gload16(gW1 + k0 + 32, &Bs[cur^1][ldsA1]);
    }
    bf16x8 af[4], bfr[4];
    #pragma unroll
    for (int m = 0; m < 4; ++m)
      af[m]  = *reinterpret_cast<const bf16x8*>(&As[cur][(wr*64 + m*16 + l16)*32 + 8*lhi]);
    #pragma unroll
    for (int n = 0; n < 4; ++n)
      bfr[n] = *reinterpret_cast<const bf16x8*>(&Bs[cur][(wc*64 + n*16 + l16)*32 + 8*lhi]);
    #pragma unroll
    for (int m = 0; m < 4; ++m){
      #pragma unroll
      for (int n = 0; n < 4; ++n){
        acc[m][n] = mfma16(af[m], bfr[n], acc[m][n]);
      }
    }
    cur ^= 1;
  }

  const int row0 = brow + wr*64;
  const int col0 = bcol + wc*64;
  #pragma unroll
  for (int m = 0; m < 4; ++m){
    #pragma unroll
    for (int n = 0; n < 4; ++n){
      #pragma unroll
      for (int r = 0; r < 4; ++r){
        int row = row0 + m*16 + 4*lhi + r;
        int col = col0 + n*16 + l16;
        float v = acc[m][n][r];
        if constexpr (HAS_BIAS) v += bias[col];
        if constexpr (RELU)     v = fmaxf(v, 0.0f);
        if constexpr (HAS_RES)  v += res[(size_t)row * N + col];
        if constexpr (OUT_BF16) ((u16*)outp)[(size_t)row * N + col] = f2bf(v);
        else                    ((float*)outp)[(size_t)row * N + col] = v;
      }
    }
  }
}

// ---------------- causal flash attention (DS-pressure-reduced) ----------------
// grid (32 bh, 32 qt); XCD-local (bh%8), LPT (qt = 31-by). exp2-domain softmax with
// Q pre-scaled by 0.125*log2(e); defer-max (vote; exact math, p<=1); l-reduce at
// epilogue. Vt: packed b32 transpose writes, granule-XOR (k>>3)^(d>>3), pitch 80.
// Ps: granule-XOR (k>>3)^(q&7), pitch 80, b128 reads. setprio around MFMA.
__global__ __launch_bounds__(256) void attn_kernel(const u16* __restrict__ qkv,
                                                   u16* __restrict__ att){
  const int bh = blockIdx.x;
  const int qt = 31 - blockIdx.y;
  const int bb = bh >> 4, hh = bh & 15;
  const int tid = threadIdx.x;
  const int wid = tid >> 6, lane = tid & 63;
  const int l16 = lane & 15, lhi = lane >> 4;
  const u16* base = qkv + (size_t)bb * 2048 * 3072 + (size_t)hh * 192;

  __shared__ u16 Ks[64*72];     //  9216 B
  __shared__ u16 Vt[64*80];     // 10240 B
  __shared__ u16 Ps[4*16*80];   // 10240 B

  // K staging: row sr, chunks sc, sc+4
  const int sr = tid >> 2;
  const int sc = tid & 3;
  const u16* kstage = base + (size_t)sr * 3072 + sc*8;
  // V staging: row pair {2va, 2va+1}, d-chunk vb (lanes 0..7 cover 128B runs)
  const int va = tid >> 3;
  const int vb = tid & 7;
  const u16* vstage = base + (size_t)(2*va) * 3072 + 128 + vb*8;
  const int vch = ((va >> 2) ^ vb) * 8 + 2*(va & 3);   // swizzled k-offset within row

  const int qrow0 = qt * 64 + wid * 16;

  const float QSCALE = 0.125f * 1.44269504f;   // log2(e)/8 -> exp2 domain
  bf16x8 qf[2];
  {
    const u16* qp = base + (size_t)(qrow0 + l16) * 3072 + 64 + 8*lhi;
    qf[0] = scale_bf16x8(*reinterpret_cast<const bf16x8*>(qp), QSCALE);
    qf[1] = scale_bf16x8(*reinterpret_cast<const bf16x8*>(qp + 32), QSCALE);
  }

  f32x4 o[4] = {};
  float m_r[4], l_part[4];
  #pragma unroll
  for (int r = 0; r < 4; ++r){ m_r[r] = -INFINITY; l_part[r] = 0.0f; }

  const int nkt = qt + 1;

  uint4 kd0, kd1, vd0, vd1;
  kd0 = *reinterpret_cast<const uint4*>(kstage);
  kd1 = *reinterpret_cast<const uint4*>(kstage + 32);
  vd0 = *reinterpret_cast<const uint4*>(vstage);
  vd1 = *reinterpret_cast<const uint4*>(vstage + 3072);

  for (int kt = 0; kt < nkt; ++kt){
    __syncthreads();             // all waves done reading previous tile
    *reinterpret_cast<uint4*>(&Ks[sr*72 + sc*8])      = kd0;
    *reinterpret_cast<uint4*>(&Ks[sr*72 + sc*8 + 32]) = kd1;
    {
      u32 w0[4] = {vd0.x, vd0.y, vd0.z, vd0.w};
      u32 w1[4] = {vd1.x, vd1.y, vd1.z, vd1.w};
      #pragma unroll
      for (int jj = 0; jj < 8; ++jj){
        u32 e0 = (w0[jj>>1] >> (16*(jj&1))) & 0xFFFFu;
        u32 e1 = (w1[jj>>1] >> (16*(jj&1))) & 0xFFFFu;
        int d = vb*8 + jj;
        *reinterpret_cast<u32*>(&Vt[d*80 + vch]) = e0 | (e1 << 16);
      }
    }
    __syncthreads();             // tile staged

    if (kt + 1 < nkt){           // prefetch next tile during compute
      const u16* kp = kstage + (size_t)(kt + 1) * 64 * 3072;
      const u16* vp = vstage + (size_t)(kt + 1) * 64 * 3072;
      kd0 = *reinterpret_cast<const uint4*>(kp);
      kd1 = *reinterpret_cast<const uint4*>(kp + 32);
      vd0 = *reinterpret_cast<const uint4*>(vp);
      vd1 = *reinterpret_cast<const uint4*>(vp + 3072);
    }

    const int kb = kt * 64;

    // ---- S' = Q'K^T (already in exp2 domain) ----
    f32x4 s_acc[4] = {};
    __builtin_amdgcn_s_setprio(1);
    #pragma unroll
    for (int f = 0; f < 4; ++f){
      const u16* kp = &Ks[(f*16 + l16)*72 + 8*lhi];
      bf16x8 k0 = *reinterpret_cast<const bf16x8*>(kp);
      bf16x8 k1 = *reinterpret_cast<const bf16x8*>(kp + 32);
      s_acc[f] = mfma16(qf[0], k0, s_acc[f]);
      s_acc[f] = mfma16(qf[1], k1, s_acc[f]);
    }
    __builtin_amdgcn_s_setprio(0);

    float sc_[4][4];
    #pragma unroll
    for (int f = 0; f < 4; ++f){
      #pragma unroll
      for (int r = 0; r < 4; ++r) sc_[f][r] = s_acc[f][r];
    }

    if (kt == nkt - 1){          // diagonal tile: causal mask
      #pragma unroll
      for (int f = 0; f < 4; ++f){
        int col = kb + f*16 + l16;
        #pragma unroll
        for (int r = 0; r < 4; ++r){
          int row = qrow0 + 4*lhi + r;
          if (col > row) sc_[f][r] = -INFINITY;
        }
      }
    }

    // ---- defer-max online softmax (exact; p<=1 always) ----
    float mxl[4];
    bool need = false;
    #pragma unroll
    for (int r = 0; r < 4; ++r){
      mxl[r] = fmaxf(fmaxf(sc_[0][r], sc_[1][r]), fmaxf(sc_[2][r], sc_[3][r]));
      need |= (mxl[r] > m_r[r]);
    }
    if (__any(need)){            // rare after tile 0: full reduce + rescale
      #pragma unroll
      for (int r = 0; r < 4; ++r){
        float mx = mxl[r];
        #pragma unroll
        for (int m = 1; m < 16; m <<= 1) mx = fmaxf(mx, __shfl_xor(mx, m, 64));
        float mnew = fmaxf(m_r[r], mx);
        float al = exp2f(m_r[r] - mnew);
        m_r[r] = mnew;
        l_part[r] *= al;
        #pragma unroll
        for (int n = 0; n < 4; ++n) o[n][r] *= al;
      }
    }
    float p[4][4];
    #pragma unroll
    for (int r = 0; r < 4; ++r){
      float s0 = 0.0f;
      #pragma unroll
      for (int f = 0; f < 4; ++f){ p[f][r] = exp2f(sc_[f][r] - m_r[r]); s0 += p[f][r]; }
      l_part[r] += s0;           // per-lane partial; reduced once at epilogue
    }

    // ---- P -> per-wave LDS (granule-XOR, pitch 80) ----
    #pragma unroll
    for (int f = 0; f < 4; ++f){
      const int kk = f*16 + l16;
      #pragma unroll
      for (int r = 0; r < 4; ++r){
        const int q = 4*lhi + r;
        Ps[wid*1280 + q*80 + (((kk>>3) ^ (q&7))*8) + (kk&7)] = f2bf(p[f][r]);
      }
    }
    bf16x8 pa[2];
    pa[0] = *reinterpret_cast<const bf16x8*>(&Ps[wid*1280 + l16*80 + (((lhi    ) ^ (l16&7))*8)]);
    pa[1] = *reinterpret_cast<const bf16x8*>(&Ps[wid*1280 + l16*80 + (((lhi + 4) ^ (l16&7))*8)]);

    // ---- PV: b128 reads from swizzled-transposed V ----
    __builtin_amdgcn_s_setprio(1);
    #pragma unroll
    for (int n = 0; n < 4; ++n){
      const int d = n*16 + l16;
      const int dh = d >> 3;
      #pragma unroll
      for (int s = 0; s < 2; ++s){
        bf16x8 vfr = *reinterpret_cast<const bf16x8*>(&Vt[d*80 + (((lhi + 4*s) ^ dh)*8)]);
        o[n] = mfma16(pa[s], vfr, o[n]);
      }
    }
    __builtin_amdgcn_s_setprio(0);
  }

  // ---- epilogue: single l-reduce, normalize, store ----
  float inv_l[4];
  #pragma unroll
  for (int r = 0; r < 4; ++r){
    float l = l_part[r];
    #pragma unroll
    for (int m = 1; m < 16; m <<= 1) l += __shfl_xor(l, m, 64);
    inv_l[r] = 1.0f / l;
  }
  #pragma unroll
  for (int n = 0; n < 4; ++n){
    #pragma unroll
    for (int r = 0; r < 4; ++r){
      int row = qrow0 + 4*lhi + r;
      int col = hh*64 + n*16 + l16;
      att[(size_t)(bb*2048 + row) * 1024 + col] = f2bf(o[n][r] * inv_l[r]);
    }
  }
}

extern "C" void kernel_launch(void* const* d_in, const int* in_sizes, int n_in,
                              void* d_out, int out_size, void* d_ws, size_t ws_size,
                              hipStream_t stream){
  const float* x        = (const float*)d_in[0];
  const float* ln1_w    = (const float*)d_in[1];
  const float* ln1_b    = (const float*)d_in[2];
  const float* c_proj_w = (const float*)d_in[3];
  const float* proj_w   = (const float*)d_in[4];
  const float* proj_b   = (const float*)d_in[5];
  const float* ln2_w    = (const float*)d_in[6];
  const float* ln2_b    = (const float*)d_in[7];
  const float* ffn1_w   = (const float*)d_in[8];
  const float* ffn1_b   = (const float*)d_in[9];
  const float* ffn2_w   = (const float*)d_in[10];
  const float* ffn2_b   = (const float*)d_in[11];

  // Workspace layout (80 MiB). Late-dead buffers (Wqkv/Wproj/LNb/ACT2) are placed
  // contiguously at the tail so the ffn2 split-K bf16 partials (32 MiB) can reuse them.
  char* p = (char*)d_ws;
  u16* Wff1  = (u16*)p;  p += (size_t)4096*1024*2;   //  8 MiB (dead after ffn1)
  u16* Wff2  = (u16*)p;  p += (size_t)1024*4096*2;   //  8 MiB (dead after ffn2)
  u16* QKV   = (u16*)p;  p += (size_t)4096*3072*2;   // 24 MiB (FFN1 aliases after attn+proj)
  u16* ATT   = (u16*)p;  p += (size_t)4096*1024*2;   //  8 MiB
  u16* Wqkv  = (u16*)p;  p += (size_t)3072*1024*2;   //  6 MiB (dead after qkv gemm)
  u16* Wproj = (u16*)p;  p += (size_t)1024*1024*2;   //  2 MiB (dead after proj)
  u16* LNb   = (u16*)p;  p += (size_t)4096*1024*2;   //  8 MiB (dead after ffn1)
  float* ACT2= (float*)p;                            // 16 MiB (dead after ln2)
  u16* FFN1  = QKV;
  u16* PART  = Wqkv;     // 32 MiB: Wqkv+Wproj+LNb+ACT2, all dead by ffn2 time

  cvt_kernel<<<3072, 256, 0, stream>>>(c_proj_w, Wqkv, 786432);
  cvt_kernel<<<1024, 256, 0, stream>>>(proj_w,  Wproj, 262144);
  cvt_kernel<<<4096, 256, 0, stream>>>(ffn1_w,  Wff1, 1048576);
  cvt_kernel<<<4096, 256, 0, stream>>>(ffn2_w,  Wff2, 1048576);

  ln_kernel<<<4096, 256, 0, stream>>>(x, ln1_w, ln1_b, LNb);
  gemm256<false,false,false><<<dim3(12,16,1), 512, 0, stream>>>(LNb, Wqkv, nullptr, QKV, 4096, 3072, 1024, 1024);
  attn_kernel<<<dim3(32,32), 256, 0, stream>>>(QKV, ATT);
  gemm_bt<true ,true ,false,false><<<dim3(8,32), 256, 0, stream>>>(ATT, Wproj, proj_b, x, ACT2, 4096, 1024, 1024);
  ln_kernel<<<4096, 256, 0, stream>>>(ACT2, ln2_w, ln2_b, LNb);
  gemm256<true ,true ,false><<<dim3(16,16,1), 512, 0, stream>>>(LNb, Wff1, ffn1_b, FFN1, 4096, 4096, 1024, 1024);
  gemm256<false,false,true ><<<dim3(4,16,4), 512, 0, stream>>>(FFN1, Wff2, nullptr, PART, 4096, 1024, 4096, 1024);
  reduce4_kernel<<<2048, 256, 0, stream>>>(PART, x, ffn2_b, (float*)d_out);
}